// Round 8
// 191.215 us; speedup vs baseline: 1.0702x; 1.0702x over previous
//
#include <hip/hip_runtime.h>

// ZGate, D=4, S=1, INDEX=(0,2,5,8), L=10, N=4^10=1048576, B=16.
// phase(n) = i^t, t = ((n>>18)+(n>>14)+(n>>8)+(n>>2)) & 3   (bit-pair digits of n)
// Input x: [2, N, B] float32 planar (re plane then im plane).
//
// Key insight: i^t has components in {0, +1, -1}. The real-part-only output is
//   t=0: +re   t=1: -im   t=2: -re   t=3: +im
// so each row n needs exactly ONE input plane (halves read traffic), and the
// "multiply" is a sign-bit XOR. The complex path is plane-swap + sign XOR.
//
// NOTE: __builtin_nontemporal_store requires a NATIVE clang vector type
// (ext_vector_type). HIP's uint4 is a HIP_vector_type struct and does NOT
// compile (verified: hipcc error, round 3). Keep v4u below.

#define NSTATES (1u << 20)          // 4^10
#define BATCH   16u
#define NB      (NSTATES * BATCH)   // floats per plane = 16,777,216

typedef unsigned int v4u __attribute__((ext_vector_type(4)));

__device__ __forceinline__ unsigned phase_t(unsigned n) {
    return ((n >> 18) + (n >> 14) + (n >> 8) + (n >> 2)) & 3u;
}

// Real-part-only output: out[n,b] = Re(i^t * x[n,b]), N*B floats.
// One v4u (4 floats of one n's batch row) per thread; reads ONE plane only.
__global__ __launch_bounds__(256) void zgate_real(const float* __restrict__ x,
                                                  float* __restrict__ out) {
    unsigned tid = blockIdx.x * blockDim.x + threadIdx.x;   // [0, NB/4)
    unsigned n = tid >> 2;                                  // 4 v4u-groups per n
    unsigned t = phase_t(n);

    // t odd -> imag plane; t in {1,2} -> negate (sign-bit XOR).
    const v4u* src = reinterpret_cast<const v4u*>(x) + ((t & 1u) ? NB / 4u : 0u);
    unsigned sgn = (((t + 1u) >> 1) & 1u) << 31;

    v4u v = src[tid];
    v ^= sgn;

    __builtin_nontemporal_store(v, reinterpret_cast<v4u*>(out) + tid);
}

// Interleaved complex output: out[(n*B+b)*2 + {0,1}] = (re', im'), 2*N*B floats.
//   t=0: ( re,  im)   t=1: (-im,  re)   t=2: (-re, -im)   t=3: ( im, -re)
__global__ __launch_bounds__(256) void zgate_cplx(const float* __restrict__ x,
                                                  float* __restrict__ out) {
    unsigned tid = blockIdx.x * blockDim.x + threadIdx.x;   // [0, NB/4)
    unsigned n = tid >> 2;
    unsigned t = phase_t(n);

    const v4u* x4 = reinterpret_cast<const v4u*>(x);
    v4u re = x4[tid];
    v4u im = x4[tid + NB / 4u];

    bool odd = (t & 1u) != 0u;
    v4u pr = odd ? im : re;                // source feeding the real output
    v4u pi = odd ? re : im;                // source feeding the imag output
    pr ^= (((t + 1u) >> 1) & 1u) << 31;    // re' negated for t==1,2
    pi ^= (t & 2u) << 30;                  // im' negated for t==2,3

    v4u o0, o1;
    o0.x = pr.x; o0.y = pi.x; o0.z = pr.y; o0.w = pi.y;
    o1.x = pr.z; o1.y = pi.z; o1.z = pr.w; o1.w = pi.w;

    v4u* out4 = reinterpret_cast<v4u*>(out) + (size_t)tid * 2u;
    __builtin_nontemporal_store(o0, out4);
    __builtin_nontemporal_store(o1, out4 + 1);
}

extern "C" void kernel_launch(void* const* d_in, const int* in_sizes, int n_in,
                              void* d_out, int out_size, void* d_ws, size_t ws_size,
                              hipStream_t stream) {
    const float* x = (const float*)d_in[0];
    float* out = (float*)d_out;

    const unsigned total_threads = NB / 4u;       // one v4u per thread
    dim3 block(256);
    dim3 grid(total_threads / 256u);              // 16384 blocks

    if ((unsigned)out_size >= 2u * NB) {
        zgate_cplx<<<grid, block, 0, stream>>>(x, out);
    } else {
        zgate_real<<<grid, block, 0, stream>>>(x, out);
    }
}

// Round 9
// 188.215 us; speedup vs baseline: 1.0872x; 1.0159x over previous
//
#include <hip/hip_runtime.h>

// ZGate, D=4, S=1, INDEX=(0,2,5,8), L=10, N=4^10=1048576, B=16.
// phase(n) = i^t, t = ((n>>18)+(n>>14)+(n>>8)+(n>>2)) & 3   (bit-pair digits of n)
// Input x: [2, N, B] float32 planar (re plane then im plane).
//
// Real-only output needs ONE plane per row (i^t components in {0,+1,-1}):
//   t=0: +re   t=1: -im   t=2: -re   t=3: +im      -> plane select + sign XOR.
//
// Wave-uniform plane swizzle: t depends only on n bits {2,3,8,9,14,15,18,19}.
// Map lane-varying tid bits to q and n bits {0,1,4,5} only, sourcing n bits
// {2,3} from tid bits {20,21}. Then t (and the plane base) is uniform across
// the wave -> readfirstlane puts the base in an SGPR, one memory stream per
// wave (4 x 256B chunks in a 4KB window) instead of two interleaved planes.
//
// NOTE: __builtin_nontemporal_* require NATIVE clang vector types
// (ext_vector_type). HIP's uint4 is a struct and does NOT compile (round 3).

#define NSTATES (1u << 20)          // 4^10
#define BATCH   16u
#define NB      (NSTATES * BATCH)   // floats per plane = 16,777,216

typedef unsigned int v4u __attribute__((ext_vector_type(4)));

__device__ __forceinline__ unsigned phase_t(unsigned n) {
    return ((n >> 18) + (n >> 14) + (n >> 8) + (n >> 2)) & 3u;
}

// Real-part-only output: out[n,b] = Re(i^t * x[n,b]), N*B floats.
// One v4u per thread at swizzled index i (bijection on [0, 2^22)):
//   i[3:0]  = tid[3:0]    (q within row, n bits 0-1)
//   i[5:4]  = tid[21:20]  (n bits 2-3 — the only t-relevant low bits)
//   i[21:6] = tid[19:4]
__global__ __launch_bounds__(256) void zgate_real(const float* __restrict__ x,
                                                  float* __restrict__ out) {
    unsigned tid = blockIdx.x * blockDim.x + threadIdx.x;   // [0, NB/4)
    unsigned i = (tid & 0xFu) | ((tid >> 16) & 0x30u) | ((tid << 2) & 0x3FFFC0u);
    unsigned n = i >> 2;                                    // 4 v4u-groups per n

    // t is wave-uniform by construction of i -> hoist to SGPR.
    unsigned t = __builtin_amdgcn_readfirstlane(phase_t(n));

    // t odd -> imag plane; t in {1,2} -> negate (sign-bit XOR).
    const v4u* src = reinterpret_cast<const v4u*>(x) + ((t & 1u) ? NB / 4u : 0u);
    unsigned sgn = (((t + 1u) >> 1) & 1u) << 31;

    v4u v = __builtin_nontemporal_load(src + i);
    v ^= sgn;

    __builtin_nontemporal_store(v, reinterpret_cast<v4u*>(out) + i);
}

// Interleaved complex output: out[(n*B+b)*2 + {0,1}] = (re', im'), 2*N*B floats.
//   t=0: ( re,  im)   t=1: (-im,  re)   t=2: (-re, -im)   t=3: ( im, -re)
__global__ __launch_bounds__(256) void zgate_cplx(const float* __restrict__ x,
                                                  float* __restrict__ out) {
    unsigned tid = blockIdx.x * blockDim.x + threadIdx.x;   // [0, NB/4)
    unsigned n = tid >> 2;
    unsigned t = phase_t(n);

    const v4u* x4 = reinterpret_cast<const v4u*>(x);
    v4u re = x4[tid];
    v4u im = x4[tid + NB / 4u];

    bool odd = (t & 1u) != 0u;
    v4u pr = odd ? im : re;                // source feeding the real output
    v4u pi = odd ? re : im;                // source feeding the imag output
    pr ^= (((t + 1u) >> 1) & 1u) << 31;    // re' negated for t==1,2
    pi ^= (t & 2u) << 30;                  // im' negated for t==2,3

    v4u o0, o1;
    o0.x = pr.x; o0.y = pi.x; o0.z = pr.y; o0.w = pi.y;
    o1.x = pr.z; o1.y = pi.z; o1.z = pr.w; o1.w = pi.w;

    v4u* out4 = reinterpret_cast<v4u*>(out) + (size_t)tid * 2u;
    __builtin_nontemporal_store(o0, out4);
    __builtin_nontemporal_store(o1, out4 + 1);
}

extern "C" void kernel_launch(void* const* d_in, const int* in_sizes, int n_in,
                              void* d_out, int out_size, void* d_ws, size_t ws_size,
                              hipStream_t stream) {
    const float* x = (const float*)d_in[0];
    float* out = (float*)d_out;

    const unsigned total_threads = NB / 4u;       // one v4u per thread
    dim3 block(256);
    dim3 grid(total_threads / 256u);              // 16384 blocks

    if ((unsigned)out_size >= 2u * NB) {
        zgate_cplx<<<grid, block, 0, stream>>>(x, out);
    } else {
        zgate_real<<<grid, block, 0, stream>>>(x, out);
    }
}

// Round 11
// 186.534 us; speedup vs baseline: 1.0970x; 1.0090x over previous
//
#include <hip/hip_runtime.h>

// ZGate, D=4, S=1, INDEX=(0,2,5,8), L=10, N=4^10=1048576, B=16.
// phase(n) = i^t, t = ((n>>18)+(n>>14)+(n>>8)+(n>>2)) & 3   (bit-pair digits of n)
// Input x: [2, N, B] float32 planar (re plane then im plane).
//
// Real-only output needs ONE plane per row (i^t components in {0,+1,-1}):
//   t=0: +re   t=1: -im   t=2: -re   t=3: +im      -> plane select + sign XOR.
//
// v3: 4 chunks (64B) per thread. Element index e (16B units) is a bijection:
//   e[3:0]  = tid[3:0]      (lane)        e[5:4] = k (unroll index — the ONLY
//   e[7:6]  = tid[5:4]      (lane)                 t-relevant low bits of n)
//   e[21:8] = tid[19:6]
// => t_k = (base + k) & 3 with base wave-uniform -> SGPR (readfirstlane);
//    plane select + sign are scalar; each wave streams a contiguous 4KB
//    window with 4 outstanding 16B loads per lane (MLP=4).
//
// NOTE: __builtin_nontemporal_* require NATIVE clang vector types
// (ext_vector_type). HIP's uint4 is a struct and does NOT compile (round 3).

#define NSTATES (1u << 20)          // 4^10
#define BATCH   16u
#define NB      (NSTATES * BATCH)   // floats per plane = 16,777,216

typedef unsigned int v4u __attribute__((ext_vector_type(4)));

__device__ __forceinline__ unsigned phase_t(unsigned n) {
    return ((n >> 18) + (n >> 14) + (n >> 8) + (n >> 2)) & 3u;
}

// Real-part-only output: out[n,b] = Re(i^t * x[n,b]), N*B floats.
__global__ __launch_bounds__(256) void zgate_real(const float* __restrict__ x,
                                                  float* __restrict__ out) {
    unsigned tid = blockIdx.x * blockDim.x + threadIdx.x;   // [0, 2^20)
    unsigned e0 = (tid & 0xFu) | ((tid << 2) & 0x3FFFC0u);  // k=0 chunk index
    unsigned n0 = e0 >> 2;

    // n0 bits {2,3} are zero by construction; remaining t-terms are
    // wave-uniform -> hoist to SGPR once.
    unsigned base = __builtin_amdgcn_readfirstlane(
        ((n0 >> 18) + (n0 >> 14) + (n0 >> 8)) & 3u);

    const v4u* xr = reinterpret_cast<const v4u*>(x);
    v4u* o4 = reinterpret_cast<v4u*>(out);

    v4u v[4];
    unsigned sg[4];
#pragma unroll
    for (unsigned k = 0; k < 4; ++k) {
        unsigned t = (base + k) & 3u;                       // scalar
        const v4u* src = xr + ((t & 1u) ? NB / 4u : 0u);    // scalar select
        sg[k] = (((t + 1u) >> 1) & 1u) << 31;
        v[k] = __builtin_nontemporal_load(src + (e0 + (k << 4u)));
    }
#pragma unroll
    for (unsigned k = 0; k < 4; ++k) {
        v[k] ^= sg[k];
        __builtin_nontemporal_store(v[k], o4 + (e0 + (k << 4u)));
    }
}

// Interleaved complex output: out[(n*B+b)*2 + {0,1}] = (re', im'), 2*N*B floats.
//   t=0: ( re,  im)   t=1: (-im,  re)   t=2: (-re, -im)   t=3: ( im, -re)
__global__ __launch_bounds__(256) void zgate_cplx(const float* __restrict__ x,
                                                  float* __restrict__ out) {
    unsigned tid = blockIdx.x * blockDim.x + threadIdx.x;   // [0, NB/4)
    unsigned n = tid >> 2;
    unsigned t = phase_t(n);

    const v4u* x4 = reinterpret_cast<const v4u*>(x);
    v4u re = x4[tid];
    v4u im = x4[tid + NB / 4u];

    bool odd = (t & 1u) != 0u;
    v4u pr = odd ? im : re;                // source feeding the real output
    v4u pi = odd ? re : im;                // source feeding the imag output
    pr ^= (((t + 1u) >> 1) & 1u) << 31;    // re' negated for t==1,2
    pi ^= (t & 2u) << 30;                  // im' negated for t==2,3

    v4u o0, o1;
    o0.x = pr.x; o0.y = pi.x; o0.z = pr.y; o0.w = pi.y;
    o1.x = pr.z; o1.y = pi.z; o1.z = pr.w; o1.w = pi.w;

    v4u* out4 = reinterpret_cast<v4u*>(out) + (size_t)tid * 2u;
    __builtin_nontemporal_store(o0, out4);
    __builtin_nontemporal_store(o1, out4 + 1);
}

extern "C" void kernel_launch(void* const* d_in, const int* in_sizes, int n_in,
                              void* d_out, int out_size, void* d_ws, size_t ws_size,
                              hipStream_t stream) {
    const float* x = (const float*)d_in[0];
    float* out = (float*)d_out;

    if ((unsigned)out_size >= 2u * NB) {
        const unsigned total_threads = NB / 4u;   // one v4u per thread
        zgate_cplx<<<dim3(total_threads / 256u), dim3(256), 0, stream>>>(x, out);
    } else {
        const unsigned total_threads = NB / 16u;  // four v4u per thread
        zgate_real<<<dim3(total_threads / 256u), dim3(256), 0, stream>>>(x, out);
    }
}